// Round 1
// baseline (88.396 us; speedup 1.0000x reference)
//
#include <hip/hip_runtime.h>

// Problem constants (from setup_inputs):
//   b=1, n_l=4096, l=16, nh=1, nv=4, f=1, nh_sz=9, nt=16
//   n = 65536 fine points, K = 144 candidates/cell
#define N_L   4096
#define NT    16
#define NV    4
#define NHSZ  9
#define KCAND 144
#define MASKV 1.0e6f
#define CUT   0.01f
#define BIG   3.0e38f

// ---------------------------------------------------------------------------
// Pass 1: per-coarse-cell "any masked point?" flag.  One wave per cell,
// lane i reads mask[cell*64 + i] (l*nh*nv = 64 floats per cell), ballot-OR.
// ---------------------------------------------------------------------------
__global__ __launch_bounds__(256) void flag_kernel(const float* __restrict__ mask,
                                                   int* __restrict__ flags) {
    int gid  = blockIdx.x * 256 + threadIdx.x;
    int cell = gid >> 6;
    int lane = gid & 63;
    if (cell < N_L) {
        float m = mask[cell * 64 + lane];
        unsigned long long b = __ballot(m != 0.0f);
        if (lane == 0) flags[cell] = (b != 0ULL) ? 1 : 0;
    }
}

// ---------------------------------------------------------------------------
// Pass 2: one thread per (cell, target) row.
//   fast path (all 9 neighbor cells mask-clean): single top-3 scan over the
//   144 dist values shared across all 4 variables; gather 3 x-float4s after.
//   slow path: per-variable masked top-3 (general semantics).
// Tie-break: strict '<' insert while scanning k ascending == lax.top_k's
// lower-index-first rule.
// ---------------------------------------------------------------------------
__global__ __launch_bounds__(256) void interp_kernel(
    const float* __restrict__ x,      // (65536, 4)  == (n_l, 16 pts, 4 vars)
    const float* __restrict__ mask,   // (65536, 4)
    const float* __restrict__ dist,   // (4096, 16, 144)
    const int*   __restrict__ nh_idx, // (4096, 9)
    const int*   __restrict__ flags,  // (4096,)
    float*       __restrict__ out)    // (65536, 4)
{
    const int tid = blockIdx.x * 256 + threadIdx.x;   // 0..65535 = (c, t)
    const int c   = tid >> 4;

    int  cells[NHSZ];
    bool clean = true;
#pragma unroll
    for (int j = 0; j < NHSZ; ++j) {
        cells[j] = nh_idx[c * NHSZ + j];
        clean &= (flags[cells[j]] == 0);
    }

    const float4* dp = (const float4*)(dist + (size_t)tid * KCAND);
    const float4* xc = (const float4*)x;     // index: cell*16 + p  (4 vars)
    const float4* mc = (const float4*)mask;  // index: cell*16 + p

    float4 result;

    if (clean) {
        // ---- fast path: one selection shared by all 4 variables ----
        float d0 = BIG, d1 = BIG, d2 = BIG;
        int   i0 = 0,   i1 = 0,   i2 = 0;

#pragma unroll 6
        for (int q = 0; q < KCAND / 4; ++q) {
            float4 dd = dp[q];
            const float de[4] = {dd.x, dd.y, dd.z, dd.w};
            const int kb = q * 4;
#pragma unroll
            for (int e = 0; e < 4; ++e) {
                float d = de[e];
                int   k = kb + e;
                bool c0 = d < d0, c1 = d < d1, c2 = d < d2;
                d2 = c1 ? d1 : (c2 ? d : d2);
                i2 = c1 ? i1 : (c2 ? k : i2);
                d1 = c0 ? d0 : (c1 ? d : d1);
                i1 = c0 ? i0 : (c1 ? k : i1);
                d0 = c0 ? d  : d0;
                i0 = c0 ? k  : i0;
            }
        }

        // gather the 3 winners' x vectors (all 4 vars at once)
        int j0 = i0 >> 4, p0 = i0 & 15;
        int j1 = i1 >> 4, p1 = i1 & 15;
        int j2 = i2 >> 4, p2 = i2 & 15;
        float4 xa = xc[cells[j0] * 16 + p0];
        float4 xb = xc[cells[j1] * 16 + p1];
        float4 xd = xc[cells[j2] * 16 + p2];

        float v0 = fmaxf(d0, CUT), v1 = fmaxf(d1, CUT), v2 = fmaxf(d2, CUT);
        float w0 = 1.0f / (v0 * v0);
        float w1 = 1.0f / (v1 * v1);
        float w2 = 1.0f / (v2 * v2);
        float inv = 1.0f / (w0 + w1 + w2);

        result.x = (xa.x * w0 + xb.x * w1 + xd.x * w2) * inv;
        result.y = (xa.y * w0 + xb.y * w1 + xd.y * w2) * inv;
        result.z = (xa.z * w0 + xb.z * w1 + xd.z * w2) * inv;
        result.w = (xa.w * w0 + xb.w * w1 + xd.w * w2) * inv;
    } else {
        // ---- slow path: per-variable masked selection ----
        float sd[NV][3];
        int   si[NV][3];
#pragma unroll
        for (int v = 0; v < NV; ++v) {
            sd[v][0] = sd[v][1] = sd[v][2] = BIG;
            si[v][0] = si[v][1] = si[v][2] = 0;
        }
        for (int q = 0; q < KCAND / 4; ++q) {
            float4 dd = dp[q];
            const float de[4] = {dd.x, dd.y, dd.z, dd.w};
#pragma unroll
            for (int e = 0; e < 4; ++e) {
                int k = q * 4 + e;
                int j = k >> 4, p = k & 15;
                float4 m4 = mc[cells[j] * 16 + p];
                const float me[4] = {m4.x, m4.y, m4.z, m4.w};
#pragma unroll
                for (int v = 0; v < NV; ++v) {
                    float dm = fmaf(me[v], MASKV, de[e]);
                    bool c0 = dm < sd[v][0], c1 = dm < sd[v][1], c2 = dm < sd[v][2];
                    sd[v][2] = c1 ? sd[v][1] : (c2 ? dm : sd[v][2]);
                    si[v][2] = c1 ? si[v][1] : (c2 ? k  : si[v][2]);
                    sd[v][1] = c0 ? sd[v][0] : (c1 ? dm : sd[v][1]);
                    si[v][1] = c0 ? si[v][0] : (c1 ? k  : si[v][1]);
                    sd[v][0] = c0 ? dm : sd[v][0];
                    si[v][0] = c0 ? k  : si[v][0];
                }
            }
        }
        float res[NV];
#pragma unroll
        for (int v = 0; v < NV; ++v) {
            float acc = 0.0f, wsum = 0.0f;
#pragma unroll
            for (int s = 0; s < 3; ++s) {
                int k = si[v][s];
                int j = k >> 4, p = k & 15;
                float xv = x[cells[j] * 64 + p * 4 + v];
                float dv = fmaxf(sd[v][s], CUT);
                float w  = 1.0f / (dv * dv);
                acc  += xv * w;
                wsum += w;
            }
            res[v] = acc / wsum;
        }
        result = make_float4(res[0], res[1], res[2], res[3]);
    }

    ((float4*)out)[tid] = result;
}

extern "C" void kernel_launch(void* const* d_in, const int* in_sizes, int n_in,
                              void* d_out, int out_size, void* d_ws, size_t ws_size,
                              hipStream_t stream) {
    const float* x      = (const float*)d_in[0];   // 262144 f32
    const float* mask   = (const float*)d_in[1];   // 262144 f32
    const float* dist   = (const float*)d_in[2];   // 9437184 f32
    const int*   nh_idx = (const int*)d_in[3];     // 36864 i32
    float*       out    = (float*)d_out;           // 262144 f32
    int*         flags  = (int*)d_ws;              // 4096 i32 scratch

    // Pass 1: per-cell mask flags (one wave per cell).
    flag_kernel<<<(N_L * 64) / 256, 256, 0, stream>>>(mask, flags);

    // Pass 2: interpolation, one thread per (cell, target) row.
    interp_kernel<<<(N_L * NT) / 256, 256, 0, stream>>>(x, mask, dist, nh_idx,
                                                        flags, out);
}

// Round 2
// 88.293 us; speedup vs baseline: 1.0012x; 1.0012x over previous
//
#include <hip/hip_runtime.h>

// Problem constants (from setup_inputs):
//   b=1, n_l=4096, l=16, nh=1, nv=4, f=1, nh_sz=9, nt=16
//   n = 65536 fine points, K = 144 candidates/cell, rows = n_l*nt = 65536
#define N_L   4096
#define NT    16
#define NV    4
#define NHSZ  9
#define KCAND 144
#define MASKV 1.0e6f
#define CUT   0.01f
#define BIG   3.0e38f

// lexicographic (d, idx): true if (da,ia) ranks before (db,ib).
// Matches jax.lax.top_k's lowest-index-first tie-break.
__device__ __forceinline__ bool lex_lt(float da, int ia, float db, int ib) {
    return (da < db) || ((da == db) && (ia < ib));
}

// One block = 256 threads = 64 rows (4 lanes per row) = 4 coarse cells.
// Lane sub (=t&3) owns variable sub in the epilogue.
__global__ __launch_bounds__(256) void interp_kernel(
    const float* __restrict__ x,      // (65536 pts, 4 vars)
    const float* __restrict__ mask,   // (65536 pts, 4 vars)
    const float* __restrict__ dist,   // (65536 rows, 144)
    const int*   __restrict__ nh_idx, // (4096, 9)
    float*       __restrict__ out)    // (65536 rows, 4 vars)
{
    __shared__ int s_cells[4 * NHSZ]; // 4 local cells x 9 neighbor cell ids
    __shared__ int s_dirty[4];        // per local cell: any masked point in nbhd?

    const int t    = threadIdx.x;
    const int row0 = blockIdx.x * 64; // 64 rows per block
    const int c0   = row0 >> 4;       // 4 cells per block

    if (t < 4) s_dirty[t] = 0;
    if (t < 4 * NHSZ) s_cells[t] = nh_idx[c0 * NHSZ + t];
    __syncthreads();

    // Cooperative mask check: 36 neighbor entries x 64 mask words = 2304 floats.
    // Thread t reads 9 coalesced floats; dirty cells flagged via LDS atomicOr
    // (never fires on the bench input: mask == 0).
#pragma unroll
    for (int i = 0; i < 9; ++i) {
        int f = t + 256 * i;          // 0..2303
        int e = f >> 6;               // neighbor entry 0..35
        int w = f & 63;               // word within cell's 64 mask floats
        float m = mask[s_cells[e] * 64 + w];
        if (m != 0.0f) atomicOr(&s_dirty[e / 9], 1);
    }
    __syncthreads();

    const int row = row0 + (t >> 2);
    const int sub = t & 3;
    const int lc  = (t >> 2) >> 4;    // local cell 0..3
    const int* cells = &s_cells[lc * NHSZ];

    if (s_dirty[lc] == 0) {
        // ---- fast path: selection shared across the 4 variables ----
        // Lane sub scans k = 4*sub + 16*m + e  (m=0..8, e=0..3): monotonic in k,
        // so strict '<' insertion is lexicographic within the lane.
        const float4* dp = (const float4*)(dist + (size_t)row * KCAND);
        float d0 = BIG, d1 = BIG, d2 = BIG;
        int   i0 = 0,   i1 = 0,   i2 = 0;
#pragma unroll
        for (int m = 0; m < 9; ++m) {
            float4 dd = dp[sub + 4 * m];
            const float de[4] = {dd.x, dd.y, dd.z, dd.w};
            const int kb = 4 * sub + 16 * m;
#pragma unroll
            for (int e = 0; e < 4; ++e) {
                float d = de[e];
                int   k = kb + e;
                bool c0_ = d < d0, c1_ = d < d1, c2_ = d < d2;
                d2 = c1_ ? d1 : (c2_ ? d : d2);
                i2 = c1_ ? i1 : (c2_ ? k : i2);
                d1 = c0_ ? d0 : (c1_ ? d : d1);
                i1 = c0_ ? i0 : (c1_ ? k : i1);
                d0 = c0_ ? d  : d0;
                i0 = c0_ ? k  : i0;
            }
        }

        // Butterfly merge across the quad (xor 1, then xor 2); after both
        // steps every lane of the quad holds the row's global top-3.
#pragma unroll
        for (int mm = 0; mm < 2; ++mm) {
            const int msk = 1 << mm;
            float ed0 = __shfl_xor(d0, msk);
            float ed1 = __shfl_xor(d1, msk);
            float ed2 = __shfl_xor(d2, msk);
            int   ei0 = __shfl_xor(i0, msk);
            int   ei1 = __shfl_xor(i1, msk);
            int   ei2 = __shfl_xor(i2, msk);
            // (3,3) merge network keeping smallest 3, lexicographic order:
            bool cA = lex_lt(d0, i0, ed0, ei0);
            float lo0d = cA ? d0 : ed0;  int lo0i = cA ? i0 : ei0;
            float hi0d = cA ? ed0 : d0;  int hi0i = cA ? ei0 : i0;
            bool cB = lex_lt(d1, i1, ed1, ei1);
            float lo1d = cB ? d1 : ed1;  int lo1i = cB ? i1 : ei1;
            float hi1d = cB ? ed1 : d1;  int hi1i = cB ? ei1 : i1;
            bool cC = lex_lt(d2, i2, ed2, ei2);
            float lo2d = cC ? d2 : ed2;  int lo2i = cC ? i2 : ei2;
            // r0 = lo0 ; r1 = min(hi0, lo1) ; r2 = min(max(hi0, lo1), lo2)
            bool cD = lex_lt(hi0d, hi0i, lo1d, lo1i);
            float r1d = cD ? hi0d : lo1d; int r1i = cD ? hi0i : lo1i;
            float t2d = cD ? lo1d : hi0d; int t2i = cD ? lo1i : hi0i;
            bool cE = lex_lt(t2d, t2i, lo2d, lo2i);
            float r2d = cE ? t2d : lo2d;  int r2i = cE ? t2i : lo2i;
            d0 = lo0d; i0 = lo0i;
            d1 = r1d;  i1 = r1i;
            d2 = r2d;  i2 = r2i;
        }

        // Epilogue: lane sub emits variable sub  ->  coalesced float stores.
        float v0 = fmaxf(d0, CUT), v1 = fmaxf(d1, CUT), v2 = fmaxf(d2, CUT);
        float w0 = 1.0f / (v0 * v0);
        float w1 = 1.0f / (v1 * v1);
        float w2 = 1.0f / (v2 * v2);
        float inv = 1.0f / (w0 + w1 + w2);
        int j0 = i0 >> 4, p0 = i0 & 15;
        int j1 = i1 >> 4, p1 = i1 & 15;
        int j2 = i2 >> 4, p2 = i2 & 15;
        float xa = x[cells[j0] * 64 + p0 * 4 + sub];
        float xb = x[cells[j1] * 64 + p1 * 4 + sub];
        float xd = x[cells[j2] * 64 + p2 * 4 + sub];
        out[row * 4 + sub] = (xa * w0 + xb * w1 + xd * w2) * inv;
    } else {
        // ---- slow path (general mask semantics): lane sub scans its own
        // variable's masked distances over all 144 candidates, k ascending.
        const float* dr = dist + (size_t)row * KCAND;
        float d0 = BIG, d1 = BIG, d2 = BIG;
        int   i0 = 0,   i1 = 0,   i2 = 0;
        for (int k = 0; k < KCAND; ++k) {
            int j = k >> 4, p = k & 15;
            float dm = fmaf(mask[cells[j] * 64 + p * 4 + sub], MASKV, dr[k]);
            bool c0_ = dm < d0, c1_ = dm < d1, c2_ = dm < d2;
            d2 = c1_ ? d1 : (c2_ ? dm : d2);
            i2 = c1_ ? i1 : (c2_ ? k  : i2);
            d1 = c0_ ? d0 : (c1_ ? dm : d1);
            i1 = c0_ ? i0 : (c1_ ? k  : i1);
            d0 = c0_ ? dm : d0;
            i0 = c0_ ? k  : i0;
        }
        float v0 = fmaxf(d0, CUT), v1 = fmaxf(d1, CUT), v2 = fmaxf(d2, CUT);
        float w0 = 1.0f / (v0 * v0);
        float w1 = 1.0f / (v1 * v1);
        float w2 = 1.0f / (v2 * v2);
        float inv = 1.0f / (w0 + w1 + w2);
        float xa = x[cells[i0 >> 4] * 64 + (i0 & 15) * 4 + sub];
        float xb = x[cells[i1 >> 4] * 64 + (i1 & 15) * 4 + sub];
        float xd = x[cells[i2 >> 4] * 64 + (i2 & 15) * 4 + sub];
        out[row * 4 + sub] = (xa * w0 + xb * w1 + xd * w2) * inv;
    }
}

extern "C" void kernel_launch(void* const* d_in, const int* in_sizes, int n_in,
                              void* d_out, int out_size, void* d_ws, size_t ws_size,
                              hipStream_t stream) {
    const float* x      = (const float*)d_in[0];   // 262144 f32
    const float* mask   = (const float*)d_in[1];   // 262144 f32
    const float* dist   = (const float*)d_in[2];   // 9437184 f32
    const int*   nh_idx = (const int*)d_in[3];     // 36864 i32
    float*       out    = (float*)d_out;           // 262144 f32

    // 65536 rows x 4 lanes/row = 262144 threads; 64 rows (4 cells) per block.
    interp_kernel<<<(N_L * NT * 4) / 256, 256, 0, stream>>>(x, mask, dist,
                                                            nh_idx, out);
}